// Round 1
// baseline (883.656 us; speedup 1.0000x reference)
//
#include <hip/hip_runtime.h>
#include <math.h>

#define BATCH    2
#define SEQ      2048
#define DIM      1024
#define HEADS    16
#define HEAD_DIM 64
#define K_NEI    64
#define QKV_DIM  3072
#define MROWS    (BATCH * SEQ)   // 4096
#define ATT_SCALE 0.125f         // 1/sqrt(64)

// C[m,n] = sum_k A[m*K+k] * B[n*K+k] + bias[n]   (both row-major, contract on last dim)
// M, N multiples of 64; K multiple of 16. No bounds checks needed for our shapes.
template<int BM, int BN, int BK>
__global__ __launch_bounds__(256)
void gemm_nt_bias(const float* __restrict__ A, const float* __restrict__ B,
                  const float* __restrict__ bias, float* __restrict__ C,
                  int M, int N, int K) {
  __shared__ float As[BK][BM + 4];   // +4 keeps float4 reads 16B-aligned, stride 68 -> 2-way banks (free)
  __shared__ float Bs[BK][BN + 4];
  const int tid = threadIdx.x;
  const int bm = blockIdx.y * BM;
  const int bn = blockIdx.x * BN;
  const int tx = tid & 15;         // 0..15 -> 4-col group
  const int ty = tid >> 4;         // 0..15 -> 4-row group
  // loader: 256 threads cover 64 rows x 16 k-floats via float4
  const int lrow = tid >> 2;          // 0..63
  const int lk   = (tid & 3) * 4;     // 0,4,8,12

  float acc[4][4] = {};
  for (int k0 = 0; k0 < K; k0 += BK) {
    float4 a = *(const float4*)(A + (size_t)(bm + lrow) * K + k0 + lk);
    float4 b = *(const float4*)(B + (size_t)(bn + lrow) * K + k0 + lk);
    As[lk + 0][lrow] = a.x; As[lk + 1][lrow] = a.y;
    As[lk + 2][lrow] = a.z; As[lk + 3][lrow] = a.w;
    Bs[lk + 0][lrow] = b.x; Bs[lk + 1][lrow] = b.y;
    Bs[lk + 2][lrow] = b.z; Bs[lk + 3][lrow] = b.w;
    __syncthreads();
#pragma unroll
    for (int kk = 0; kk < BK; kk++) {
      float4 av = *(const float4*)&As[kk][ty * 4];
      float4 bv = *(const float4*)&Bs[kk][tx * 4];
      float ar[4] = {av.x, av.y, av.z, av.w};
      float br[4] = {bv.x, bv.y, bv.z, bv.w};
#pragma unroll
      for (int i = 0; i < 4; i++)
#pragma unroll
        for (int j = 0; j < 4; j++)
          acc[i][j] += ar[i] * br[j];
    }
    __syncthreads();
  }
#pragma unroll
  for (int i = 0; i < 4; i++) {
    const int row = bm + ty * 4 + i;
#pragma unroll
    for (int j = 0; j < 4; j++) {
      const int col = bn + tx * 4 + j;
      C[(size_t)row * N + col] = acc[i][j] + bias[col];
    }
  }
}

// One 64-thread wave per (b,h,q). qkv layout: [B, S, 3*DIM] with the 3*DIM axis
// split as t*1024 + h*64 + d (t=0:q, 1:k, 2:v). Output ao: [B, S, H*D].
__global__ __launch_bounds__(64)
void attn_kernel(const float* __restrict__ qkv, const int* __restrict__ routes,
                 float* __restrict__ ao) {
  const int lane = threadIdx.x;            // 0..63
  const int idx  = blockIdx.x;             // ((b*HEADS + h)*SEQ + q)
  const int q    = idx % SEQ;
  const int bh   = idx / SEQ;
  const int h    = bh % HEADS;
  const int b    = bh / HEADS;

  __shared__ float ks[K_NEI][HEAD_DIM + 1];   // reused for K then V
  __shared__ float qs[HEAD_DIM];
  __shared__ float ps[K_NEI];
  __shared__ int   rts[K_NEI];

  const size_t row_base = (size_t)b * SEQ;
  const int    hoff     = h * HEAD_DIM;

  qs[lane]  = qkv[(row_base + q) * QKV_DIM + hoff + lane];
  rts[lane] = routes[q * K_NEI + lane];
  __syncthreads();

  // stage gathered K rows (coalesced: lane = d)
#pragma unroll 4
  for (int r = 0; r < K_NEI; r++) {
    const int row = rts[r];
    ks[r][lane] = qkv[(row_base + row) * QKV_DIM + DIM + hoff + lane];
  }
  __syncthreads();

  // lane = neighbor index: score dot product from LDS
  float s = 0.f;
#pragma unroll
  for (int d = 0; d < HEAD_DIM; d++) s += qs[d] * ks[lane][d];
  s *= ATT_SCALE;

  // wave-wide softmax (64 lanes)
  float m = s;
#pragma unroll
  for (int off = 32; off > 0; off >>= 1) m = fmaxf(m, __shfl_xor(m, off));
  float p = __expf(s - m);
  float sum = p;
#pragma unroll
  for (int off = 32; off > 0; off >>= 1) sum += __shfl_xor(sum, off);
  p /= sum;

  __syncthreads();             // all score reads of ks done before overwrite
  ps[lane] = p;

  // stage gathered V rows into the same buffer
#pragma unroll 4
  for (int r = 0; r < K_NEI; r++) {
    const int row = rts[r];
    ks[r][lane] = qkv[(row_base + row) * QKV_DIM + 2 * DIM + hoff + lane];
  }
  __syncthreads();

  // lane = d: weighted V sum
  float o = 0.f;
#pragma unroll
  for (int r = 0; r < K_NEI; r++) o += ps[r] * ks[r][lane];

  ao[(row_base + q) * DIM + hoff + lane] = o;
}

extern "C" void kernel_launch(void* const* d_in, const int* in_sizes, int n_in,
                              void* d_out, int out_size, void* d_ws, size_t ws_size,
                              hipStream_t stream) {
  const float* x      = (const float*)d_in[0];   // [B,S,DIM]
  const int*   routes = (const int*)  d_in[1];   // [S,K]
  const float* qkv_w  = (const float*)d_in[2];   // [3*DIM, DIM]
  const float* qkv_b  = (const float*)d_in[3];   // [3*DIM]
  const float* out_w  = (const float*)d_in[4];   // [DIM, DIM]
  const float* out_b  = (const float*)d_in[5];   // [DIM]
  float* out = (float*)d_out;                    // [B,S,DIM]

  float* qkv = (float*)d_ws;                         // MROWS * QKV_DIM
  float* ao  = qkv + (size_t)MROWS * QKV_DIM;        // MROWS * DIM

  // 1) QKV projection: [4096,1024] x [3072,1024]^T -> [4096,3072]
  dim3 g1(QKV_DIM / 64, MROWS / 64);
  gemm_nt_bias<64, 64, 16><<<g1, 256, 0, stream>>>(x, qkv_w, qkv_b, qkv,
                                                   MROWS, QKV_DIM, DIM);

  // 2) gathered attention -> ao [B,S,H*D]
  attn_kernel<<<BATCH * HEADS * SEQ, 64, 0, stream>>>(qkv, routes, ao);

  // 3) output projection: [4096,1024] x [1024,1024]^T -> [4096,1024]
  dim3 g2(DIM / 64, MROWS / 64);
  gemm_nt_bias<64, 64, 16><<<g2, 256, 0, stream>>>(ao, out_w, out_b, out,
                                                   MROWS, DIM, DIM);
}

// Round 2
// 718.015 us; speedup vs baseline: 1.2307x; 1.2307x over previous
//
#include <hip/hip_runtime.h>
#include <math.h>

#define BATCH    2
#define SEQ      2048
#define DIM      1024
#define HEADS    16
#define HEAD_DIM 64
#define K_NEI    64
#define QKV_DIM  3072
#define MROWS    (BATCH * SEQ)   // 4096
#define ATT_SCALE 0.125f         // 1/sqrt(64)

// C[m,n] = sum_k A[m*K+k] * B[n*K+k] + bias[n]   (both row-major, contract on last dim)
template<int BM, int BN, int BK>
__global__ __launch_bounds__(256)
void gemm_nt_bias(const float* __restrict__ A, const float* __restrict__ B,
                  const float* __restrict__ bias, float* __restrict__ C,
                  int M, int N, int K) {
  __shared__ float As[BK][BM + 4];
  __shared__ float Bs[BK][BN + 4];
  const int tid = threadIdx.x;
  const int bm = blockIdx.y * BM;
  const int bn = blockIdx.x * BN;
  const int tx = tid & 15;
  const int ty = tid >> 4;
  const int lrow = tid >> 2;
  const int lk   = (tid & 3) * 4;

  float acc[4][4] = {};
  for (int k0 = 0; k0 < K; k0 += BK) {
    float4 a = *(const float4*)(A + (size_t)(bm + lrow) * K + k0 + lk);
    float4 b = *(const float4*)(B + (size_t)(bn + lrow) * K + k0 + lk);
    As[lk + 0][lrow] = a.x; As[lk + 1][lrow] = a.y;
    As[lk + 2][lrow] = a.z; As[lk + 3][lrow] = a.w;
    Bs[lk + 0][lrow] = b.x; Bs[lk + 1][lrow] = b.y;
    Bs[lk + 2][lrow] = b.z; Bs[lk + 3][lrow] = b.w;
    __syncthreads();
#pragma unroll
    for (int kk = 0; kk < BK; kk++) {
      float4 av = *(const float4*)&As[kk][ty * 4];
      float4 bv = *(const float4*)&Bs[kk][tx * 4];
      float ar[4] = {av.x, av.y, av.z, av.w};
      float br[4] = {bv.x, bv.y, bv.z, bv.w};
#pragma unroll
      for (int i = 0; i < 4; i++)
#pragma unroll
        for (int j = 0; j < 4; j++)
          acc[i][j] += ar[i] * br[j];
    }
    __syncthreads();
  }
#pragma unroll
  for (int i = 0; i < 4; i++) {
    const int row = bm + ty * 4 + i;
#pragma unroll
    for (int j = 0; j < 4; j++) {
      const int col = bn + tx * 4 + j;
      C[(size_t)row * N + col] = acc[i][j] + bias[col];
    }
  }
}

// Barrier-free gathered attention. 4 waves/block, one (b,h,q) per wave.
// Score phase: lane = neighbor r, direct global float4 reads of own K row.
// V phase: lane = d, coalesced global reads, p/route broadcast from LDS.
// All LDS producer->consumer pairs are within one wave => no __syncthreads.
__global__ __launch_bounds__(256, 4)
void attn_kernel(const float* __restrict__ qkv, const int* __restrict__ routes,
                 float* __restrict__ ao) {
  const int lane = threadIdx.x & 63;
  const int w    = threadIdx.x >> 6;

  // XCD-locality swizzle: assuming round-robin block->XCD, give each XCD a
  // contiguous q-band (Cantor routes are q-local) across all (b,h).
  const int i    = blockIdx.x;          // 0..16383
  const int xcd  = i & 7;
  const int j    = i >> 3;              // 0..2047
  const int bh   = j >> 6;              // 0..31
  const int qsub = j & 63;              // 0..63
  const int qblk = xcd * 64 + qsub;     // 0..511
  const int q    = qblk * 4 + w;        // 0..2047
  const int h    = bh & 15;
  const int b    = bh >> 4;

  __shared__ __align__(16) float qs[4][64];
  __shared__ float ps[4][64];
  __shared__ int   rts[4][64];

  const size_t row_base = (size_t)b * SEQ;
  const int    hoff     = h * HEAD_DIM;

  // q vector into per-wave LDS slice (for broadcast in the dot)
  qs[w][lane] = qkv[(row_base + q) * QKV_DIM + hoff + lane];
  const int rt = routes[q * K_NEI + lane];   // this lane's own neighbor row
  rts[w][lane] = rt;

  // ---- scores: lane r dots q against K[rt] directly from global ----
  const float4* krow = (const float4*)(qkv + (row_base + rt) * QKV_DIM + DIM + hoff);
  float s = 0.f;
#pragma unroll
  for (int dq = 0; dq < 16; dq++) {
    float4 kv = krow[dq];
    float4 qv = *(const float4*)&qs[w][dq * 4];
    s += kv.x * qv.x; s += kv.y * qv.y; s += kv.z * qv.z; s += kv.w * qv.w;
  }
  s *= ATT_SCALE;

  // ---- 64-lane softmax ----
  float m = s;
#pragma unroll
  for (int off = 32; off > 0; off >>= 1) m = fmaxf(m, __shfl_xor(m, off));
  float p = __expf(s - m);
  float sum = p;
#pragma unroll
  for (int off = 32; off > 0; off >>= 1) sum += __shfl_xor(sum, off);
  p /= sum;
  ps[w][lane] = p;

  // ---- output: lane = d, coalesced V reads, uniform LDS broadcasts ----
  const float* vbase = qkv + row_base * QKV_DIM + 2 * DIM + hoff + lane;
  float o = 0.f;
#pragma unroll
  for (int r = 0; r < K_NEI; r++) {
    o += ps[w][r] * vbase[(size_t)rts[w][r] * QKV_DIM];
  }
  ao[(row_base + q) * DIM + hoff + lane] = o;
}

extern "C" void kernel_launch(void* const* d_in, const int* in_sizes, int n_in,
                              void* d_out, int out_size, void* d_ws, size_t ws_size,
                              hipStream_t stream) {
  const float* x      = (const float*)d_in[0];
  const int*   routes = (const int*)  d_in[1];
  const float* qkv_w  = (const float*)d_in[2];
  const float* qkv_b  = (const float*)d_in[3];
  const float* out_w  = (const float*)d_in[4];
  const float* out_b  = (const float*)d_in[5];
  float* out = (float*)d_out;

  float* qkv = (float*)d_ws;
  float* ao  = qkv + (size_t)MROWS * QKV_DIM;

  dim3 g1(QKV_DIM / 64, MROWS / 64);
  gemm_nt_bias<64, 64, 16><<<g1, 256, 0, stream>>>(x, qkv_w, qkv_b, qkv,
                                                   MROWS, QKV_DIM, DIM);

  attn_kernel<<<(BATCH * HEADS * SEQ) / 4, 256, 0, stream>>>(qkv, routes, ao);

  dim3 g2(DIM / 64, MROWS / 64);
  gemm_nt_bias<64, 64, 16><<<g2, 256, 0, stream>>>(ao, out_w, out_b, out,
                                                   MROWS, DIM, DIM);
}

// Round 3
// 253.338 us; speedup vs baseline: 3.4881x; 2.8342x over previous
//
#include <hip/hip_runtime.h>
#include <math.h>

#define BATCH    2
#define SEQ      2048
#define DIM      1024
#define HEADS    16
#define HEAD_DIM 64
#define K_NEI    64
#define QKV_DIM  3072
#define MROWS    (BATCH * SEQ)   // 4096
#define ATT_SCALE 0.125f

typedef __attribute__((ext_vector_type(8))) short short8;   // 8 bf16 in 4 VGPRs
typedef __attribute__((ext_vector_type(4))) float floatx4;

__device__ inline float bf2f(unsigned short s) {
  union { unsigned int i; float f; } u; u.i = ((unsigned int)s) << 16; return u.f;
}
__device__ inline unsigned short f2bf(float f) {   // round-to-nearest-even
  union { float f; unsigned int i; } u; u.f = f;
  unsigned int r = u.i + 0x7fffu + ((u.i >> 16) & 1u);
  return (unsigned short)(r >> 16);
}

__device__ inline void async_copy16(const void* g, void* l) {
  __builtin_amdgcn_global_load_lds(
      (const __attribute__((address_space(1))) unsigned int*)g,
      (__attribute__((address_space(3))) unsigned int*)l, 16, 0, 0);
}

// fused fp32 -> bf16 cast of three tensors (sizes multiples of 4)
__global__ __launch_bounds__(256)
void cast3(const float* __restrict__ a, int na4,
           const float* __restrict__ b, int nb4,
           const float* __restrict__ c, int nc4,
           unsigned short* __restrict__ oa,
           unsigned short* __restrict__ ob,
           unsigned short* __restrict__ oc) {
  const int total = na4 + nb4 + nc4;
  for (int i = blockIdx.x * blockDim.x + threadIdx.x; i < total;
       i += gridDim.x * blockDim.x) {
    const float* src; unsigned short* dst; int idx;
    if (i < na4)            { src = a; dst = oa; idx = i; }
    else if (i < na4 + nb4) { src = b; dst = ob; idx = i - na4; }
    else                    { src = c; dst = oc; idx = i - na4 - nb4; }
    float4 v = *(const float4*)(src + (size_t)idx * 4);
    ushort4 o;
    o.x = f2bf(v.x); o.y = f2bf(v.y); o.z = f2bf(v.z); o.w = f2bf(v.w);
    *(ushort4*)(dst + (size_t)idx * 4) = o;
  }
}

// C[m,n] = sum_k A[m,k]*B[n,k] + bias[n]; A:[M,K] bf16, B:[N,K] bf16, C fp32.
// 128x128 tile, BK=32, 4 waves (2x2), 4x4 MFMA frags/wave, m97 structure.
// M,N multiples of 128; K multiple of 32.
__global__ __launch_bounds__(256)
void gemm_bt_bf16(const unsigned short* __restrict__ A,
                  const unsigned short* __restrict__ B,
                  const float* __restrict__ bias, float* __restrict__ C,
                  int M, int N, int K) {
  __shared__ unsigned short As[128 * 32];   // 8 KB, row-major [row][k] (no pad: global_load_lds)
  __shared__ unsigned short Bs[128 * 32];

  const int tid  = threadIdx.x;
  const int lane = tid & 63;
  const int w    = tid >> 6;          // 0..3
  const int wr   = w >> 1;            // wave row half
  const int wc   = w & 1;             // wave col half
  const int bm   = blockIdx.y * 128;
  const int bn   = blockIdx.x * 128;

  // staging addresses: each wave stages 32 rows of As and Bs (2 instrs each)
  const int srow = w * 32 + (lane >> 2);       // + t*16
  const int scol = (lane & 3) * 8;
  const unsigned short* ga = A + (size_t)(bm + srow) * K + scol;
  const unsigned short* gb = B + (size_t)(bn + srow) * K + scol;
  unsigned short* la = As + (w * 32) * 32;     // wave-uniform LDS base
  unsigned short* lb = Bs + (w * 32) * 32;

  // fragment read offsets
  const int frow = lane & 15;                  // m (or n) within 16-tile
  const int fk   = (lane >> 4) * 8;            // k offset within 32

  floatx4 acc[4][4] = {};

  for (int k0 = 0; k0 < K; k0 += 32) {
    async_copy16(ga + k0,            la);
    async_copy16(ga + k0 + 16 * K,   la + 16 * 32);
    async_copy16(gb + k0,            lb);
    async_copy16(gb + k0 + 16 * K,   lb + 16 * 32);
    __syncthreads();   // drains vmcnt: LDS tiles complete

    short8 af[4], bf[4];
#pragma unroll
    for (int i = 0; i < 4; i++)
      af[i] = *(const short8*)&As[(wr * 64 + i * 16 + frow) * 32 + fk];
#pragma unroll
    for (int j = 0; j < 4; j++)
      bf[j] = *(const short8*)&Bs[(wc * 64 + j * 16 + frow) * 32 + fk];
#pragma unroll
    for (int i = 0; i < 4; i++)
#pragma unroll
      for (int j = 0; j < 4; j++)
        acc[i][j] = __builtin_amdgcn_mfma_f32_16x16x32_bf16(af[i], bf[j], acc[i][j], 0, 0, 0);
    __syncthreads();   // all reads done before next-iter overwrite
  }

  // epilogue: C/D layout col = lane&15, row = (lane>>4)*4 + reg
  const int crow = (lane >> 4) * 4;
  const int ccol = lane & 15;
#pragma unroll
  for (int j = 0; j < 4; j++) {
    const int gcol = bn + wc * 64 + j * 16 + ccol;
    const float bj = bias[gcol];
#pragma unroll
    for (int i = 0; i < 4; i++) {
      const int grow = bm + wr * 64 + i * 16 + crow;
      float* cp = C + (size_t)grow * N + gcol;
#pragma unroll
      for (int r = 0; r < 4; r++)
        cp[(size_t)r * N] = acc[i][j][r] + bj;
    }
  }
}

// Barrier-free gathered attention on bf16 qkv; fp32 accumulate; bf16 out.
__global__ __launch_bounds__(256, 4)
void attn_kernel(const unsigned short* __restrict__ qkv,
                 const int* __restrict__ routes,
                 unsigned short* __restrict__ ao) {
  const int lane = threadIdx.x & 63;
  const int w    = threadIdx.x >> 6;

  const int i    = blockIdx.x;          // 0..16383
  const int xcd  = i & 7;
  const int j    = i >> 3;
  const int bh   = j >> 6;
  const int qsub = j & 63;
  const int qblk = xcd * 64 + qsub;
  const int q    = qblk * 4 + w;
  const int h    = bh & 15;
  const int b    = bh >> 4;

  __shared__ __align__(16) float qs[4][64];
  __shared__ float ps[4][64];
  __shared__ int   rts[4][64];

  const size_t row_base = (size_t)b * SEQ;
  const int    hoff     = h * HEAD_DIM;

  qs[w][lane] = bf2f(qkv[(row_base + q) * QKV_DIM + hoff + lane]);
  const int rt = routes[q * K_NEI + lane];
  rts[w][lane] = rt;

  // ---- scores: lane r reads its K row (64 bf16 = 8 x 16B) ----
  const uint4* krow = (const uint4*)(qkv + (row_base + rt) * QKV_DIM + DIM + hoff);
  float s = 0.f;
#pragma unroll
  for (int dq = 0; dq < 8; dq++) {
    uint4 kv = krow[dq];
    const float* qp = &qs[w][dq * 8];
    unsigned int uu[4] = {kv.x, kv.y, kv.z, kv.w};
#pragma unroll
    for (int t = 0; t < 4; t++) {
      s += bf2f((unsigned short)(uu[t] & 0xffff)) * qp[t * 2];
      s += bf2f((unsigned short)(uu[t] >> 16))    * qp[t * 2 + 1];
    }
  }
  s *= ATT_SCALE;

  // ---- 64-lane softmax ----
  float m = s;
#pragma unroll
  for (int off = 32; off > 0; off >>= 1) m = fmaxf(m, __shfl_xor(m, off));
  float p = __expf(s - m);
  float sum = p;
#pragma unroll
  for (int off = 32; off > 0; off >>= 1) sum += __shfl_xor(sum, off);
  p /= sum;
  ps[w][lane] = p;

  // ---- output: lane = d, coalesced bf16 reads, LDS broadcasts ----
  const unsigned short* vbase = qkv + row_base * QKV_DIM + 2 * DIM + hoff + lane;
  float o = 0.f;
#pragma unroll
  for (int r = 0; r < K_NEI; r++) {
    o += ps[w][r] * bf2f(vbase[(size_t)rts[w][r] * QKV_DIM]);
  }
  ao[(row_base + q) * DIM + hoff + lane] = f2bf(o);
}

extern "C" void kernel_launch(void* const* d_in, const int* in_sizes, int n_in,
                              void* d_out, int out_size, void* d_ws, size_t ws_size,
                              hipStream_t stream) {
  const float* x      = (const float*)d_in[0];
  const int*   routes = (const int*)  d_in[1];
  const float* qkv_w  = (const float*)d_in[2];
  const float* qkv_b  = (const float*)d_in[3];
  const float* out_w  = (const float*)d_in[4];
  const float* out_b  = (const float*)d_in[5];
  float* out = (float*)d_out;

  // workspace layout (bf16 buffers)
  unsigned short* qkvb = (unsigned short*)d_ws;                  // 4096*3072
  unsigned short* aob  = qkvb + (size_t)MROWS * QKV_DIM;         // 4096*1024
  unsigned short* xb   = aob  + (size_t)MROWS * DIM;             // 4096*1024
  unsigned short* wb   = xb   + (size_t)MROWS * DIM;             // 3072*1024
  unsigned short* owb  = wb   + (size_t)QKV_DIM * DIM;           // 1024*1024
  float* qkvf = (float*)(owb + (size_t)DIM * DIM);               // 4096*3072 fp32

  // 1) cast x, qkv_w, out_w to bf16
  cast3<<<1024, 256, 0, stream>>>(x, MROWS * DIM / 4,
                                  qkv_w, QKV_DIM * DIM / 4,
                                  out_w, DIM * DIM / 4,
                                  xb, wb, owb);

  // 2) QKV projection (bf16 MFMA) -> fp32 qkvf, then it is consumed as... no:
  //    write fp32? attention reads bf16. GEMM writes fp32 C; cast to bf16 inline
  //    would need another pass. Instead: GEMM -> fp32 qkvf, cast -> qkvb.
  {
    dim3 g(QKV_DIM / 128, MROWS / 128);
    gemm_bt_bf16<<<g, 256, 0, stream>>>(xb, wb, qkv_b, qkvf, MROWS, QKV_DIM, DIM);
  }
  // cast qkvf -> qkvb (reuse cast3 with dummy tiny segments)
  cast3<<<2048, 256, 0, stream>>>(qkvf, MROWS * QKV_DIM / 4,
                                  qkv_b, 0, qkv_b, 0,
                                  qkvb, qkvb, qkvb);

  // 3) gathered attention -> aob (bf16)
  attn_kernel<<<(BATCH * HEADS * SEQ) / 4, 256, 0, stream>>>(qkvb, routes, aob);

  // 4) output projection (bf16 MFMA) -> out fp32
  {
    dim3 g(DIM / 128, MROWS / 128);
    gemm_bt_bf16<<<g, 256, 0, stream>>>(aob, owb, out_b, out, MROWS, DIM, DIM);
  }
}

// Round 4
// 249.258 us; speedup vs baseline: 3.5451x; 1.0164x over previous
//
#include <hip/hip_runtime.h>
#include <math.h>

#define BATCH    2
#define SEQ      2048
#define DIM      1024
#define HEADS    16
#define HEAD_DIM 64
#define K_NEI    64
#define QKV_DIM  3072
#define MROWS    (BATCH * SEQ)   // 4096
#define ATT_SCALE 0.125f

typedef _Float16 half8  __attribute__((ext_vector_type(8)));
typedef _Float16 half4  __attribute__((ext_vector_type(4)));
typedef _Float16 half2t __attribute__((ext_vector_type(2)));
typedef float    floatx4 __attribute__((ext_vector_type(4)));

__device__ inline float rl_f(float v, int lane) {
  union { float f; int i; } u; u.f = v;
  u.i = __builtin_amdgcn_readlane(u.i, lane);
  return u.f;
}

__device__ inline void async_copy16(const void* g, void* l) {
  __builtin_amdgcn_global_load_lds(
      (const __attribute__((address_space(1))) unsigned int*)g,
      (__attribute__((address_space(3))) unsigned int*)l, 16, 0, 0);
}

// fused fp32 -> f16 cast of three tensors (sizes in float4 groups)
__global__ __launch_bounds__(256)
void cast3(const float* __restrict__ a, int na4,
           const float* __restrict__ b, int nb4,
           const float* __restrict__ c, int nc4,
           _Float16* __restrict__ oa, _Float16* __restrict__ ob,
           _Float16* __restrict__ oc) {
  const int total = na4 + nb4 + nc4;
  for (int i = blockIdx.x * blockDim.x + threadIdx.x; i < total;
       i += gridDim.x * blockDim.x) {
    const float* src; _Float16* dst; int idx;
    if (i < na4)            { src = a; dst = oa; idx = i; }
    else if (i < na4 + nb4) { src = b; dst = ob; idx = i - na4; }
    else                    { src = c; dst = oc; idx = i - na4 - nb4; }
    float4 v = *(const float4*)(src + (size_t)idx * 4);
    half4 o;
    o[0] = (_Float16)v.x; o[1] = (_Float16)v.y;
    o[2] = (_Float16)v.z; o[3] = (_Float16)v.w;
    *(half4*)(dst + (size_t)idx * 4) = o;
  }
}

// C[m,n] = sum_k A[m,k]*B[n,k] + bias[n]; A:[M,K] f16, B:[N,K] f16.
// HALF_OUT: swapped-operand MFMA -> lane holds 4 consecutive cols -> half4 stores.
// else: fp32 output, verified coalesced dword epilogue.
template<bool HALF_OUT>
__global__ __launch_bounds__(256)
void gemm_bt_f16(const _Float16* __restrict__ A, const _Float16* __restrict__ B,
                 const float* __restrict__ bias, void* __restrict__ Cv,
                 int M, int N, int K) {
  __shared__ _Float16 As[128 * 32];   // 8 KB
  __shared__ _Float16 Bs[128 * 32];

  const int tid  = threadIdx.x;
  const int lane = tid & 63;
  const int w    = tid >> 6;
  const int wr   = w >> 1;
  const int wc   = w & 1;
  const int bm   = blockIdx.y * 128;
  const int bn   = blockIdx.x * 128;

  const int srow = w * 32 + (lane >> 2);
  const int scol = (lane & 3) * 8;
  const _Float16* ga = A + (size_t)(bm + srow) * K + scol;
  const _Float16* gb = B + (size_t)(bn + srow) * K + scol;
  _Float16* la = As + (w * 32) * 32;
  _Float16* lb = Bs + (w * 32) * 32;

  const int frow = lane & 15;
  const int fk   = (lane >> 4) * 8;

  floatx4 acc[4][4] = {};

  for (int k0 = 0; k0 < K; k0 += 32) {
    async_copy16(ga + k0,          la);
    async_copy16(ga + k0 + 16 * K, la + 16 * 32);
    async_copy16(gb + k0,          lb);
    async_copy16(gb + k0 + 16 * K, lb + 16 * 32);
    __syncthreads();

    half8 af[4], bf[4];
#pragma unroll
    for (int i = 0; i < 4; i++)
      af[i] = *(const half8*)&As[(wr * 64 + i * 16 + frow) * 32 + fk];
#pragma unroll
    for (int j = 0; j < 4; j++)
      bf[j] = *(const half8*)&Bs[(wc * 64 + j * 16 + frow) * 32 + fk];
#pragma unroll
    for (int i = 0; i < 4; i++)
#pragma unroll
      for (int j = 0; j < 4; j++) {
        if (HALF_OUT)
          acc[i][j] = __builtin_amdgcn_mfma_f32_16x16x32_f16(bf[j], af[i], acc[i][j], 0, 0, 0);
        else
          acc[i][j] = __builtin_amdgcn_mfma_f32_16x16x32_f16(af[i], bf[j], acc[i][j], 0, 0, 0);
      }
    __syncthreads();
  }

  if (HALF_OUT) {
    // D'[n][m]: lane&15 = row m, (lane>>4)*4+reg = col n -> half4 store per frag
    _Float16* C = (_Float16*)Cv;
    const int mloc = lane & 15;
    const int nloc = (lane >> 4) * 4;
#pragma unroll
    for (int j = 0; j < 4; j++) {
      const int gcol = bn + wc * 64 + j * 16 + nloc;
      float4 bj = *(const float4*)(bias + gcol);
#pragma unroll
      for (int i = 0; i < 4; i++) {
        const int grow = bm + wr * 64 + i * 16 + mloc;
        half4 hv;
        hv[0] = (_Float16)(acc[i][j][0] + bj.x);
        hv[1] = (_Float16)(acc[i][j][1] + bj.y);
        hv[2] = (_Float16)(acc[i][j][2] + bj.z);
        hv[3] = (_Float16)(acc[i][j][3] + bj.w);
        *(half4*)(C + (size_t)grow * N + gcol) = hv;
      }
    }
  } else {
    float* C = (float*)Cv;
    const int crow = (lane >> 4) * 4;
    const int ccol = lane & 15;
#pragma unroll
    for (int j = 0; j < 4; j++) {
      const int gcol = bn + wc * 64 + j * 16 + ccol;
      const float bj = bias[gcol];
#pragma unroll
      for (int i = 0; i < 4; i++) {
        const int grow = bm + wr * 64 + i * 16 + crow;
        float* cp = C + (size_t)grow * N + gcol;
#pragma unroll
        for (int r = 0; r < 4; r++)
          cp[(size_t)r * N] = acc[i][j][r] + bj;
      }
    }
  }
}

// Barrier-free gathered attention on f16 qkv; fp32 accumulate; f16 out.
// Score: lane = neighbor, v_dot2_f32_f16. V: readlane-broadcast p/route,
// scalar-folded addressing, coalesced f16 loads.
__global__ __launch_bounds__(256, 4)
void attn_kernel(const _Float16* __restrict__ qkv,
                 const int* __restrict__ routes,
                 _Float16* __restrict__ ao) {
  const int lane = threadIdx.x & 63;
  const int w    = threadIdx.x >> 6;

  const int i    = blockIdx.x;          // 0..16383
  const int xcd  = i & 7;
  const int j    = i >> 3;
  const int bh   = j >> 6;
  const int qsub = j & 63;
  const int qblk = xcd * 64 + qsub;
  const int q    = qblk * 4 + w;
  const int h    = bh & 15;
  const int b    = bh >> 4;

  __shared__ __align__(16) _Float16 qs[4][64];

  const size_t row_base = (size_t)b * SEQ;
  const int    hoff     = h * HEAD_DIM;

  qs[w][lane] = qkv[(row_base + q) * QKV_DIM + hoff + lane];
  const int rt = routes[q * K_NEI + lane];

  // preload q into 8 x uint4 regs (per-wave LDS slice, wave-synchronous)
  uint4 qu[8];
#pragma unroll
  for (int t = 0; t < 8; t++) qu[t] = ((const uint4*)&qs[w][0])[t];

  // ---- scores: lane r dots q against its K row (8 x 16B global reads) ----
  const uint4* krow = (const uint4*)(qkv + (row_base + rt) * QKV_DIM + DIM + hoff);
  float s = 0.f;
#pragma unroll
  for (int dq = 0; dq < 8; dq++) {
    uint4 ku = krow[dq];
    const half2t* kp = (const half2t*)&ku;
    const half2t* qp = (const half2t*)&qu[dq];
#pragma unroll
    for (int t = 0; t < 4; t++) {
#if defined(__has_builtin) && __has_builtin(__builtin_amdgcn_fdot2)
      s = __builtin_amdgcn_fdot2(kp[t], qp[t], s, false);
#else
      s += (float)kp[t][0] * (float)qp[t][0] + (float)kp[t][1] * (float)qp[t][1];
#endif
    }
  }
  s *= ATT_SCALE;

  // ---- 64-lane softmax ----
  float m = s;
#pragma unroll
  for (int off = 32; off > 0; off >>= 1) m = fmaxf(m, __shfl_xor(m, off));
  float p = __expf(s - m);
  float sum = p;
#pragma unroll
  for (int off = 32; off > 0; off >>= 1) sum += __shfl_xor(sum, off);
  p /= sum;

  // ---- output: lane = d; p/route broadcast via readlane (SGPR operands) ----
  const _Float16* vrow = qkv + row_base * QKV_DIM + 2 * DIM + hoff + lane;
  float o0 = 0.f, o1 = 0.f, o2 = 0.f, o3 = 0.f;
#pragma unroll
  for (int r = 0; r < K_NEI; r += 4) {
    const int   i0 = __builtin_amdgcn_readlane(rt, r);
    const int   i1 = __builtin_amdgcn_readlane(rt, r + 1);
    const int   i2 = __builtin_amdgcn_readlane(rt, r + 2);
    const int   i3 = __builtin_amdgcn_readlane(rt, r + 3);
    const float p0 = rl_f(p, r),     p1 = rl_f(p, r + 1);
    const float p2 = rl_f(p, r + 2), p3 = rl_f(p, r + 3);
    o0 += p0 * (float)vrow[(size_t)i0 * QKV_DIM];
    o1 += p1 * (float)vrow[(size_t)i1 * QKV_DIM];
    o2 += p2 * (float)vrow[(size_t)i2 * QKV_DIM];
    o3 += p3 * (float)vrow[(size_t)i3 * QKV_DIM];
  }
  ao[(row_base + q) * DIM + hoff + lane] = (_Float16)((o0 + o1) + (o2 + o3));
}

extern "C" void kernel_launch(void* const* d_in, const int* in_sizes, int n_in,
                              void* d_out, int out_size, void* d_ws, size_t ws_size,
                              hipStream_t stream) {
  const float* x      = (const float*)d_in[0];
  const int*   routes = (const int*)  d_in[1];
  const float* qkv_w  = (const float*)d_in[2];
  const float* qkv_b  = (const float*)d_in[3];
  const float* out_w  = (const float*)d_in[4];
  const float* out_b  = (const float*)d_in[5];
  float* out = (float*)d_out;

  _Float16* qkvh = (_Float16*)d_ws;                       // 4096*3072
  _Float16* aoh  = qkvh + (size_t)MROWS * QKV_DIM;        // 4096*1024
  _Float16* xh   = aoh  + (size_t)MROWS * DIM;            // 4096*1024
  _Float16* wh   = xh   + (size_t)MROWS * DIM;            // 3072*1024
  _Float16* owh  = wh   + (size_t)QKV_DIM * DIM;          // 1024*1024

  // 1) cast x, qkv_w, out_w to f16
  cast3<<<1024, 256, 0, stream>>>(x, MROWS * DIM / 4,
                                  qkv_w, QKV_DIM * DIM / 4,
                                  out_w, DIM * DIM / 4,
                                  xh, wh, owh);

  // 2) QKV projection -> f16 qkvh directly (swapped-operand epilogue)
  {
    dim3 g(QKV_DIM / 128, MROWS / 128);
    gemm_bt_f16<true><<<g, 256, 0, stream>>>(xh, wh, qkv_b, qkvh,
                                             MROWS, QKV_DIM, DIM);
  }

  // 3) gathered attention -> aoh (f16)
  attn_kernel<<<(BATCH * HEADS * SEQ) / 4, 256, 0, stream>>>(qkvh, routes, aoh);

  // 4) output projection -> fp32 out
  {
    dim3 g(DIM / 128, MROWS / 128);
    gemm_bt_f16<false><<<g, 256, 0, stream>>>(aoh, owh, out_b, out,
                                              MROWS, DIM, DIM);
  }
}

// Round 5
// 222.933 us; speedup vs baseline: 3.9638x; 1.1181x over previous
//
#include <hip/hip_runtime.h>
#include <math.h>

#define BATCH    2
#define SEQ      2048
#define DIM      1024
#define HEADS    16
#define HEAD_DIM 64
#define K_NEI    64
#define QKV_DIM  3072
#define MROWS    (BATCH * SEQ)   // 4096
#define ATT_SCALE 0.125f

typedef _Float16 half8  __attribute__((ext_vector_type(8)));
typedef _Float16 half4  __attribute__((ext_vector_type(4)));
typedef _Float16 half2t __attribute__((ext_vector_type(2)));
typedef float    floatx4 __attribute__((ext_vector_type(4)));

__device__ inline void async_copy16(const void* g, void* l) {
  __builtin_amdgcn_global_load_lds(
      (const __attribute__((address_space(1))) unsigned int*)g,
      (__attribute__((address_space(3))) unsigned int*)l, 16, 0, 0);
}

__device__ inline float dot2h(half2t a, half2t b, float c) {
#if defined(__has_builtin) && __has_builtin(__builtin_amdgcn_fdot2)
  return __builtin_amdgcn_fdot2(a, b, c, false);
#else
  return c + (float)a[0] * (float)b[0] + (float)a[1] * (float)b[1];
#endif
}

// fused fp32 -> f16 cast of three tensors (sizes in float4 groups)
__global__ __launch_bounds__(256)
void cast3(const float* __restrict__ a, int na4,
           const float* __restrict__ b, int nb4,
           const float* __restrict__ c, int nc4,
           _Float16* __restrict__ oa, _Float16* __restrict__ ob,
           _Float16* __restrict__ oc) {
  const int total = na4 + nb4 + nc4;
  for (int i = blockIdx.x * blockDim.x + threadIdx.x; i < total;
       i += gridDim.x * blockDim.x) {
    const float* src; _Float16* dst; int idx;
    if (i < na4)            { src = a; dst = oa; idx = i; }
    else if (i < na4 + nb4) { src = b; dst = ob; idx = i - na4; }
    else                    { src = c; dst = oc; idx = i - na4 - nb4; }
    float4 v = *(const float4*)(src + (size_t)idx * 4);
    half4 o;
    o[0] = (_Float16)v.x; o[1] = (_Float16)v.y;
    o[2] = (_Float16)v.z; o[3] = (_Float16)v.w;
    *(half4*)(dst + (size_t)idx * 4) = o;
  }
}

// C[m,n] = sum_k A[m,k]*B[n,k] + bias[n]; A:[M,K] f16, B:[N,K] f16.
template<bool HALF_OUT>
__global__ __launch_bounds__(256)
void gemm_bt_f16(const _Float16* __restrict__ A, const _Float16* __restrict__ B,
                 const float* __restrict__ bias, void* __restrict__ Cv,
                 int M, int N, int K) {
  __shared__ _Float16 As[128 * 32];   // 8 KB
  __shared__ _Float16 Bs[128 * 32];

  const int tid  = threadIdx.x;
  const int lane = tid & 63;
  const int w    = tid >> 6;
  const int wr   = w >> 1;
  const int wc   = w & 1;
  const int bm   = blockIdx.y * 128;
  const int bn   = blockIdx.x * 128;

  const int srow = w * 32 + (lane >> 2);
  const int scol = (lane & 3) * 8;
  const _Float16* ga = A + (size_t)(bm + srow) * K + scol;
  const _Float16* gb = B + (size_t)(bn + srow) * K + scol;
  _Float16* la = As + (w * 32) * 32;
  _Float16* lb = Bs + (w * 32) * 32;

  const int frow = lane & 15;
  const int fk   = (lane >> 4) * 8;

  floatx4 acc[4][4] = {};

  for (int k0 = 0; k0 < K; k0 += 32) {
    async_copy16(ga + k0,          la);
    async_copy16(ga + k0 + 16 * K, la + 16 * 32);
    async_copy16(gb + k0,          lb);
    async_copy16(gb + k0 + 16 * K, lb + 16 * 32);
    __syncthreads();

    half8 af[4], bf[4];
#pragma unroll
    for (int i = 0; i < 4; i++)
      af[i] = *(const half8*)&As[(wr * 64 + i * 16 + frow) * 32 + fk];
#pragma unroll
    for (int j = 0; j < 4; j++)
      bf[j] = *(const half8*)&Bs[(wc * 64 + j * 16 + frow) * 32 + fk];
#pragma unroll
    for (int i = 0; i < 4; i++)
#pragma unroll
      for (int j = 0; j < 4; j++) {
        if (HALF_OUT)
          acc[i][j] = __builtin_amdgcn_mfma_f32_16x16x32_f16(bf[j], af[i], acc[i][j], 0, 0, 0);
        else
          acc[i][j] = __builtin_amdgcn_mfma_f32_16x16x32_f16(af[i], bf[j], acc[i][j], 0, 0, 0);
      }
    __syncthreads();
  }

  if (HALF_OUT) {
    _Float16* C = (_Float16*)Cv;
    const int mloc = lane & 15;
    const int nloc = (lane >> 4) * 4;
#pragma unroll
    for (int j = 0; j < 4; j++) {
      const int gcol = bn + wc * 64 + j * 16 + nloc;
      float4 bj = *(const float4*)(bias + gcol);
#pragma unroll
      for (int i = 0; i < 4; i++) {
        const int grow = bm + wr * 64 + i * 16 + mloc;
        half4 hv;
        hv[0] = (_Float16)(acc[i][j][0] + bj.x);
        hv[1] = (_Float16)(acc[i][j][1] + bj.y);
        hv[2] = (_Float16)(acc[i][j][2] + bj.z);
        hv[3] = (_Float16)(acc[i][j][3] + bj.w);
        *(half4*)(C + (size_t)grow * N + gcol) = hv;
      }
    }
  } else {
    float* C = (float*)Cv;
    const int crow = (lane >> 4) * 4;
    const int ccol = lane & 15;
#pragma unroll
    for (int j = 0; j < 4; j++) {
      const int gcol = bn + wc * 64 + j * 16 + ccol;
      const float bj = bias[gcol];
#pragma unroll
      for (int i = 0; i < 4; i++) {
        const int grow = bm + wr * 64 + i * 16 + crow;
        float* cp = C + (size_t)grow * N + gcol;
#pragma unroll
        for (int r = 0; r < 4; r++)
          cp[(size_t)r * N] = acc[i][j][r] + bj;
      }
    }
  }
}

// Quad-cooperative gathered attention (f16 qkv, fp32 accum, f16 out).
// Lane l = (group g = l>>4, chunk c = l&15). Pass t: group g loads K/V row
// routes[4t+g] as 16x8B contiguous (4x128B segments per instruction instead
// of 64 divergent lines). V rows parked in registers during score phase.
// Zero LDS, zero barriers; all reductions via xor-shuffles.
__global__ __launch_bounds__(256, 4)
void attn_kernel(const _Float16* __restrict__ qkv,
                 const int* __restrict__ routes,
                 _Float16* __restrict__ ao) {
  const int lane = threadIdx.x & 63;
  const int w    = threadIdx.x >> 6;
  const int g    = lane >> 4;          // row group 0..3
  const int c    = lane & 15;          // 8B chunk within row

  const int i    = blockIdx.x;          // 0..16383
  const int xcd  = i & 7;
  const int j    = i >> 3;
  const int bh   = j >> 6;
  const int qsub = j & 63;
  const int qblk = xcd * 64 + qsub;
  const int q    = qblk * 4 + w;
  const int h    = bh & 15;
  const int b    = bh >> 4;

  const size_t row_base = (size_t)b * SEQ;
  const int    hoff     = h * HEAD_DIM;

  // this lane's own route entry (lane = neighbor index for the shuffle source)
  const int rt = routes[q * K_NEI + lane];

  // q chunk: dims [4c, 4c+4) (same across groups -> L1 broadcast)
  const half4 qv = *(const half4*)(qkv + (row_base + q) * QKV_DIM + hoff + 4 * c);
  const half2t qv01 = { qv[0], qv[1] };
  const half2t qv23 = { qv[2], qv[3] };

  float  s_reg[16];
  half4  vv[16];

  // ---- score phase: 16 passes, 4 rows/instruction, V parked in regs ----
#pragma unroll
  for (int t = 0; t < 16; t++) {
    const int ri = __shfl(rt, 4 * t + g);              // quad-uniform row idx
    const _Float16* kp = qkv + (row_base + ri) * QKV_DIM + DIM + hoff + 4 * c;
    half4 kv = *(const half4*)kp;
    vv[t]    = *(const half4*)(kp + DIM);              // V row, +2048B offset
    half2t k01 = { kv[0], kv[1] };
    half2t k23 = { kv[2], kv[3] };
    float sp = dot2h(k23, qv23, dot2h(k01, qv01, 0.f));
    // reduce the 16-lane group's partials (lanes differ in bits 0..3)
#pragma unroll
    for (int off = 1; off < 16; off <<= 1) sp += __shfl_xor(sp, off);
    s_reg[t] = sp;
  }

  // ---- softmax over 64 scores (16 per lane x 4 groups) ----
  float m = s_reg[0];
#pragma unroll
  for (int t = 1; t < 16; t++) m = fmaxf(m, s_reg[t]);
  m = fmaxf(m, __shfl_xor(m, 16));
  m = fmaxf(m, __shfl_xor(m, 32));

  float sum = 0.f;
#pragma unroll
  for (int t = 0; t < 16; t++) {
    s_reg[t] = __expf((s_reg[t] - m) * ATT_SCALE);
    sum += s_reg[t];
  }
  sum += __shfl_xor(sum, 16);
  sum += __shfl_xor(sum, 32);
  const float rinv = 1.f / sum;

  // ---- weighted V sum (memory-free) ----
  float o0 = 0.f, o1 = 0.f, o2 = 0.f, o3 = 0.f;
#pragma unroll
  for (int t = 0; t < 16; t++) {
    const float p = s_reg[t] * rinv;
    o0 += p * (float)vv[t][0];
    o1 += p * (float)vv[t][1];
    o2 += p * (float)vv[t][2];
    o3 += p * (float)vv[t][3];
  }
  // sum the 4 groups (lanes differ in bits 4..5)
  o0 += __shfl_xor(o0, 16); o0 += __shfl_xor(o0, 32);
  o1 += __shfl_xor(o1, 16); o1 += __shfl_xor(o1, 32);
  o2 += __shfl_xor(o2, 16); o2 += __shfl_xor(o2, 32);
  o3 += __shfl_xor(o3, 16); o3 += __shfl_xor(o3, 32);

  if (g == 0) {
    half4 hv;
    hv[0] = (_Float16)o0; hv[1] = (_Float16)o1;
    hv[2] = (_Float16)o2; hv[3] = (_Float16)o3;
    *(half4*)(ao + (row_base + q) * DIM + hoff + 4 * c) = hv;
  }
}

extern "C" void kernel_launch(void* const* d_in, const int* in_sizes, int n_in,
                              void* d_out, int out_size, void* d_ws, size_t ws_size,
                              hipStream_t stream) {
  const float* x      = (const float*)d_in[0];
  const int*   routes = (const int*)  d_in[1];
  const float* qkv_w  = (const float*)d_in[2];
  const float* qkv_b  = (const float*)d_in[3];
  const float* out_w  = (const float*)d_in[4];
  const float* out_b  = (const float*)d_in[5];
  float* out = (float*)d_out;

  _Float16* qkvh = (_Float16*)d_ws;                       // 4096*3072
  _Float16* aoh  = qkvh + (size_t)MROWS * QKV_DIM;        // 4096*1024
  _Float16* xh   = aoh  + (size_t)MROWS * DIM;            // 4096*1024
  _Float16* wh   = xh   + (size_t)MROWS * DIM;            // 3072*1024
  _Float16* owh  = wh   + (size_t)QKV_DIM * DIM;          // 1024*1024

  cast3<<<1024, 256, 0, stream>>>(x, MROWS * DIM / 4,
                                  qkv_w, QKV_DIM * DIM / 4,
                                  out_w, DIM * DIM / 4,
                                  xh, wh, owh);

  {
    dim3 g(QKV_DIM / 128, MROWS / 128);
    gemm_bt_f16<true><<<g, 256, 0, stream>>>(xh, wh, qkv_b, qkvh,
                                             MROWS, QKV_DIM, DIM);
  }

  attn_kernel<<<(BATCH * HEADS * SEQ) / 4, 256, 0, stream>>>(qkvh, routes, aoh);

  {
    dim3 g(DIM / 128, MROWS / 128);
    gemm_bt_f16<false><<<g, 256, 0, stream>>>(aoh, owh, out_b, out,
                                              MROWS, DIM, DIM);
  }
}